// Round 1
// baseline (714.105 us; speedup 1.0000x reference)
//
#include <hip/hip_runtime.h>

// B=16, C=128, H=256, W=64.
// Fully fused per-(b,w) block: bf16-MFMA QKV projections, attention over H,
// final ReLU 1x1 conv. 512 threads (8 waves), 160 KiB LDS, 1 block/CU.

typedef __attribute__((ext_vector_type(8))) short short8;
typedef __attribute__((ext_vector_type(4))) float f32x4;

#define MFMA16(acc, a, b) (acc) = __builtin_amdgcn_mfma_f32_16x16x32_bf16((a), (b), (acc), 0, 0, 0)

__device__ __forceinline__ unsigned short f2b(float f) {
  unsigned u = __builtin_bit_cast(unsigned, f);
  u = (u + 0x7fffu + ((u >> 16) & 1u)) >> 16;   // RNE
  return (unsigned short)u;
}

// LDS layout (bf16, XOR-swizzled: byte ^= (row&7)<<4 -> conflict-free b128 reads)
//  XS  [128][128] @ 0    (32K): x-half, then q_pass / P-slices / att_pass
//  KS  [256][128] @ 32K  (64K): k rows over c
//  VTS [128][256] @ 96K  (64K): v^T rows (c) over g
__device__ __forceinline__ unsigned xs_addr(int h, int c) {
  return (unsigned)(((h << 7) + c) << 1) ^ (unsigned)((h & 7) << 4);
}
__device__ __forceinline__ unsigned ks_addr(int g, int c) {
  return (unsigned)(((g << 7) + c) << 1) ^ (unsigned)((g & 7) << 4);
}
__device__ __forceinline__ unsigned vts_addr(int c, int g) {
  return (unsigned)(((c << 8) + g) << 1) ^ (unsigned)((c & 7) << 4);
}

__device__ __forceinline__ short8 ldsf(const char* p, unsigned off) {
  return *(const short8*)(p + off);
}

// 16-row x 32-k weight fragment from global fp32 row-major [128][128]
__device__ __forceinline__ short8 wfrag(const float* wrow, int kk, int g4) {
  const float* p = wrow + kk * 32 + g4 * 8;
  float4 a = *(const float4*)(p);
  float4 c = *(const float4*)(p + 4);
  short8 r;
  r[0] = (short)f2b(a.x); r[1] = (short)f2b(a.y);
  r[2] = (short)f2b(a.z); r[3] = (short)f2b(a.w);
  r[4] = (short)f2b(c.x); r[5] = (short)f2b(c.y);
  r[6] = (short)f2b(c.z); r[7] = (short)f2b(c.w);
  return r;
}

__global__ __launch_bounds__(512, 1) void fused_sa(
    const float* __restrict__ rep,
    const float* __restrict__ wq, const float* __restrict__ bq,
    const float* __restrict__ wk, const float* __restrict__ bk,
    const float* __restrict__ wv, const float* __restrict__ bv,
    const float* __restrict__ wfc, const float* __restrict__ bfc,
    float* __restrict__ out)
{
  extern __shared__ char smem[];
  char* XS  = smem;
  char* KS  = smem + (32 << 10);
  char* VTS = smem + (96 << 10);

  const int t = threadIdx.x;
  const int wvid = t >> 6;          // wave 0..7
  const int l = t & 63;
  const int l16 = l & 15;
  const int g4 = l >> 4;            // 0..3
  const int ostrip = wvid << 4;     // wave's 16-wide output-channel strip

  const int bid = blockIdx.x;
  const int id = ((bid & 7) << 7) + (bid >> 3);  // XCD swizzle: 128 blocks/XCD
  const int b = id >> 6;
  const int w = id & 63;

  // per-lane biases
  const float bkv = bk[ostrip + l16];
  const float bqv = bq[ostrip + l16];
  float bvv[4], bfcv[4];
#pragma unroll
  for (int r = 0; r < 4; ++r) {
    bvv[r]  = bv[ostrip + g4 * 4 + r];
    bfcv[r] = bfc[ostrip + g4 * 4 + r];
  }
  // wfc strip fragments, held for the whole kernel
  short8 wfcf[4];
#pragma unroll
  for (int kk = 0; kk < 4; ++kk) wfcf[kk] = wfrag(wfc + (ostrip + l16) * 128, kk, g4);

  unsigned qpk[2][8][2];   // q o'-strip, bf16-packed, D layout (32 VGPRs)

  const float* repb = rep + (size_t)b * (128 * 256 * 64) + w;

  // ============ Phase A: projections (two h-halves through XS) ============
#pragma unroll
  for (int ph = 0; ph < 2; ++ph) {
    // load x half: rep[b, c, ph*128+hl, w] -> XS[hl][c] (bf16)
#pragma unroll
    for (int it = 0; it < 32; ++it) {
      int i = it * 512 + t;
      int c = i >> 7, hl = i & 127;
      float v = repb[((size_t)c * 256 + ph * 128 + hl) * 64];
      *(unsigned short*)(XS + xs_addr(hl, c)) = f2b(v);
    }
    __syncthreads();

    // --- K projection: D[h][o'] = relu(xs . wk^T + bk), o'-strip per wave ---
    {
      short8 wf[4];
#pragma unroll
      for (int kk = 0; kk < 4; ++kk) wf[kk] = wfrag(wk + (ostrip + l16) * 128, kk, g4);
#pragma unroll
      for (int mt = 0; mt < 8; ++mt) {
        f32x4 acc = {0.f, 0.f, 0.f, 0.f};
#pragma unroll
        for (int kk = 0; kk < 4; ++kk) {
          short8 a = ldsf(XS, xs_addr(mt * 16 + l16, kk * 32 + g4 * 8));
          MFMA16(acc, a, wf[kk]);
        }
        int gg = ph * 128 + mt * 16 + g4 * 4;
#pragma unroll
        for (int r = 0; r < 4; ++r) {
          float y = fmaxf(acc[r] + bkv, 0.f);
          *(unsigned short*)(KS + ks_addr(gg + r, ostrip + l16)) = f2b(y);
        }
      }
    }
    // --- Q projection: same shape, packed into registers ---
    {
      short8 wf[4];
#pragma unroll
      for (int kk = 0; kk < 4; ++kk) wf[kk] = wfrag(wq + (ostrip + l16) * 128, kk, g4);
#pragma unroll
      for (int mt = 0; mt < 8; ++mt) {
        f32x4 acc = {0.f, 0.f, 0.f, 0.f};
#pragma unroll
        for (int kk = 0; kk < 4; ++kk) {
          short8 a = ldsf(XS, xs_addr(mt * 16 + l16, kk * 32 + g4 * 8));
          MFMA16(acc, a, wf[kk]);
        }
        float y0 = fmaxf(acc[0] + bqv, 0.f);
        float y1 = fmaxf(acc[1] + bqv, 0.f);
        float y2 = fmaxf(acc[2] + bqv, 0.f);
        float y3 = fmaxf(acc[3] + bqv, 0.f);
        qpk[ph][mt][0] = (unsigned)f2b(y0) | ((unsigned)f2b(y1) << 16);
        qpk[ph][mt][1] = (unsigned)f2b(y2) | ((unsigned)f2b(y3) << 16);
      }
    }
    // --- V^T projection: D[o][h] = relu(wv . xs^T + bv), o-strip per wave ---
    {
      short8 wf[4];
#pragma unroll
      for (int kk = 0; kk < 4; ++kk) wf[kk] = wfrag(wv + (ostrip + l16) * 128, kk, g4);
#pragma unroll
      for (int nt = 0; nt < 8; ++nt) {
        f32x4 acc = {0.f, 0.f, 0.f, 0.f};
#pragma unroll
        for (int kk = 0; kk < 4; ++kk) {
          short8 bb = ldsf(XS, xs_addr(nt * 16 + l16, kk * 32 + g4 * 8));
          MFMA16(acc, wf[kk], bb);
        }
        int hcol = ph * 128 + nt * 16 + l16;
#pragma unroll
        for (int r = 0; r < 4; ++r) {
          float y = fmaxf(acc[r] + bvv[r], 0.f);
          *(unsigned short*)(VTS + vts_addr(ostrip + g4 * 4 + r, hcol)) = f2b(y);
        }
      }
    }
    __syncthreads();
  }

  // ============ Phase B: attention + final conv (two h-passes) ============
  const float SCL2 = 0.08838834764831845f * 1.4426950408889634f; // rsqrt(128)*log2(e)
#pragma unroll
  for (int p = 0; p < 2; ++p) {
    // scatter q strips into q_pass[128][128] (XS)
#pragma unroll
    for (int mt = 0; mt < 8; ++mt) {
#pragma unroll
      for (int r2 = 0; r2 < 2; ++r2) {
        unsigned pk = qpk[p][mt][r2];
        int hl = mt * 16 + g4 * 4 + r2 * 2;
        *(unsigned short*)(XS + xs_addr(hl,     ostrip + l16)) = (unsigned short)(pk & 0xffffu);
        *(unsigned short*)(XS + xs_addr(hl + 1, ostrip + l16)) = (unsigned short)(pk >> 16);
      }
    }
    __syncthreads();

    // q a-frags for this wave's 16 rows (rows wvid*16.. = this wave's slice)
    short8 qa[4];
#pragma unroll
    for (int kk = 0; kk < 4; ++kk)
      qa[kk] = ldsf(XS, xs_addr(wvid * 16 + l16, kk * 32 + g4 * 8));

    // scores s[16h][256g] = q . k^T
    f32x4 sc[16];
#pragma unroll
    for (int gt = 0; gt < 16; ++gt) {
      f32x4 acc = {0.f, 0.f, 0.f, 0.f};
#pragma unroll
      for (int kk = 0; kk < 4; ++kk) {
        short8 kb = ldsf(KS, ks_addr(gt * 16 + l16, kk * 32 + g4 * 8));
        MFMA16(acc, qa[kk], kb);
      }
      sc[gt] = acc;
    }

    // softmax over g (row = g4*4 + r; 16-lane shfl_xor reduce)
    float mx[4], rcps[4];
#pragma unroll
    for (int r = 0; r < 4; ++r) {
      float m = sc[0][r];
#pragma unroll
      for (int gt = 1; gt < 16; ++gt) m = fmaxf(m, sc[gt][r]);
      m = fmaxf(m, __shfl_xor(m, 1, 64));
      m = fmaxf(m, __shfl_xor(m, 2, 64));
      m = fmaxf(m, __shfl_xor(m, 4, 64));
      m = fmaxf(m, __shfl_xor(m, 8, 64));
      mx[r] = m;
    }
#pragma unroll
    for (int gt = 0; gt < 16; ++gt) {
#pragma unroll
      for (int r = 0; r < 4; ++r)
        sc[gt][r] = exp2f((sc[gt][r] - mx[r]) * SCL2);
    }
#pragma unroll
    for (int r = 0; r < 4; ++r) {
      float s = 0.f;
#pragma unroll
      for (int gt = 0; gt < 16; ++gt) s += sc[gt][r];
      s += __shfl_xor(s, 1, 64);
      s += __shfl_xor(s, 2, 64);
      s += __shfl_xor(s, 4, 64);
      s += __shfl_xor(s, 8, 64);
      rcps[r] = 1.0f / s;   // normalization deferred to PV output
    }

    // PV in two g-halves through the wave's private 4K slice (wave-local LDS)
    char* slice = XS + (wvid << 12);
    f32x4 zf = {0.f, 0.f, 0.f, 0.f};
    f32x4 oacc[8];
#pragma unroll
    for (int nt = 0; nt < 8; ++nt) oacc[nt] = zf;
#pragma unroll
    for (int gh = 0; gh < 2; ++gh) {
      // stage unnormalized P-half [16][128] bf16
#pragma unroll
      for (int gt8 = 0; gt8 < 8; ++gt8) {
        int gt = gh * 8 + gt8;
        int gc = gt8 * 16 + l16;
#pragma unroll
        for (int r = 0; r < 4; ++r)
          *(unsigned short*)(slice + xs_addr(g4 * 4 + r, gc)) = f2b(sc[gt][r]);
      }
#pragma unroll
      for (int kk = 0; kk < 4; ++kk) {
        short8 pa = ldsf(slice, xs_addr(l16, kk * 32 + g4 * 8));
#pragma unroll
        for (int nt = 0; nt < 8; ++nt) {
          short8 vb = ldsf(VTS, vts_addr(nt * 16 + l16, gh * 128 + kk * 32 + g4 * 8));
          MFMA16(oacc[nt], pa, vb);
        }
      }
    }
    // normalize, stage att rows [wvid*16..+16) into XS (own slice)
#pragma unroll
    for (int nt = 0; nt < 8; ++nt) {
#pragma unroll
      for (int r = 0; r < 4; ++r) {
        float y = oacc[nt][r] * rcps[r];
        *(unsigned short*)(XS + xs_addr(wvid * 16 + g4 * 4 + r, nt * 16 + l16)) = f2b(y);
      }
    }
    __syncthreads();

    // final conv: y[o-strip][h of pass] = relu(wfc . att^T + bfc)
#pragma unroll
    for (int nt = 0; nt < 8; ++nt) {
      f32x4 acc = {0.f, 0.f, 0.f, 0.f};
#pragma unroll
      for (int kk = 0; kk < 4; ++kk) {
        short8 ab = ldsf(XS, xs_addr(nt * 16 + l16, kk * 32 + g4 * 8));
        MFMA16(acc, wfcf[kk], ab);
      }
      int hg = p * 128 + nt * 16 + l16;
#pragma unroll
      for (int r = 0; r < 4; ++r) {
        int o = ostrip + g4 * 4 + r;
        float y = fmaxf(acc[r] + bfcv[r], 0.f);
        out[((size_t)(b * 128 + o) * 256 + hg) * 64 + w] = y;
      }
    }
    __syncthreads();   // att_pass dead before next pass's q_pass write
  }
}

extern "C" void kernel_launch(void* const* d_in, const int* in_sizes, int n_in,
                              void* d_out, int out_size, void* d_ws, size_t ws_size,
                              hipStream_t stream) {
  const float* rep = (const float*)d_in[0];
  const float* wq  = (const float*)d_in[1];
  const float* bq  = (const float*)d_in[2];
  const float* wk  = (const float*)d_in[3];
  const float* bk  = (const float*)d_in[4];
  const float* wv  = (const float*)d_in[5];
  const float* bv  = (const float*)d_in[6];
  const float* wfc = (const float*)d_in[7];
  const float* bfc = (const float*)d_in[8];
  (void)in_sizes; (void)n_in; (void)d_ws; (void)ws_size; (void)out_size;

  hipFuncSetAttribute((const void*)fused_sa,
                      hipFuncAttributeMaxDynamicSharedMemorySize, 160 * 1024);
  fused_sa<<<dim3(1024), dim3(512), 160 * 1024, stream>>>(
      rep, wq, bq, wk, bk, wv, bv, wfc, bfc, (float*)d_out);
}

// Round 3
// 483.823 us; speedup vs baseline: 1.4760x; 1.4760x over previous
//
#include <hip/hip_runtime.h>

// B=16, C=128, H=256, W=64.  3-kernel pipeline through bf16 workspace:
//  K1: Q/K/V = relu(Wx+b)  -> ws [b][n=h*64+w][c] bf16, written direct from MFMA D-layout
//  K2: per-(b,w) attention over H (R1-verified formulas) -> att [b][n][c] bf16
//  K3: out = relu(wfc . att^T + bfc) -> [b][o][n] fp32 coalesced

typedef __attribute__((ext_vector_type(8))) short short8;
typedef __attribute__((ext_vector_type(4))) float f32x4;

#define MFMA16(acc, a, b) (acc) = __builtin_amdgcn_mfma_f32_16x16x32_bf16((a), (b), (acc), 0, 0, 0)

__device__ __forceinline__ unsigned short f2b(float f) {
  unsigned u = __builtin_bit_cast(unsigned, f);
  u = (u + 0x7fffu + ((u >> 16) & 1u)) >> 16;   // RNE
  return (unsigned short)u;
}

// [R][128c] bf16 tile, row-XOR swizzle (R1-verified write-scalar/read-b128 pair)
__device__ __forceinline__ unsigned adr_s(int r, int c) {
  return (unsigned)(((r << 8) + (c << 1)) ^ ((r & 7) << 4));
}
// K1's XS [128j][128c]: stronger row-hash (rows written in stride-4 bursts)
__device__ __forceinline__ unsigned adr_q(int r, int c) {
  return (unsigned)(((r << 8) + (c << 1)) ^ (((r ^ (r >> 3)) & 7) << 4));
}
// V^T tile [128c][256g] — R1's exact verified formula
__device__ __forceinline__ unsigned adr_vt(int c, int g) {
  return (unsigned)(((c << 9) + (g << 1)) ^ ((c & 7) << 4));
}

__device__ __forceinline__ short8 ldsf(const char* p, unsigned off) {
  return *(const short8*)(p + off);
}

// 16-row x 32-k weight fragment from global fp32 row-major [128][128]
__device__ __forceinline__ short8 wfrag(const float* wrow, int kk, int g4) {
  const float* p = wrow + kk * 32 + g4 * 8;
  float4 a = *(const float4*)(p);
  float4 c = *(const float4*)(p + 4);
  short8 r;
  r[0] = (short)f2b(a.x); r[1] = (short)f2b(a.y);
  r[2] = (short)f2b(a.z); r[3] = (short)f2b(a.w);
  r[4] = (short)f2b(c.x); r[5] = (short)f2b(c.y);
  r[6] = (short)f2b(c.z); r[7] = (short)f2b(c.w);
  return r;
}

// ================= K1: QKV projection =================
// grid = nbc*128; block tile = 128 n.  LDS: XS [128n][128c] (32K) only.

__device__ __forceinline__ void k1_one(const float* wmat, const float* bias,
    unsigned short* dst, const char* XS,
    int brel, int n0, int wvid, int l16, int g4) {
  const int strip = wvid * 16;
  short8 wf[4];
#pragma unroll
  for (int kk = 0; kk < 4; ++kk) wf[kk] = wfrag(wmat + (strip + l16) * 128, kk, g4);
  float bv4[4];
#pragma unroll
  for (int r = 0; r < 4; ++r) bv4[r] = bias[strip + g4 * 4 + r];

#pragma unroll
  for (int nt = 0; nt < 8; ++nt) {
    f32x4 acc = {0.f, 0.f, 0.f, 0.f};
#pragma unroll
    for (int kk = 0; kk < 4; ++kk) {
      short8 xb = ldsf(XS, adr_q(nt * 16 + l16, kk * 32 + g4 * 8));
      MFMA16(acc, wf[kk], xb);   // D[o][n']: col=l16 -> n', row=g4*4+r -> o
    }
    // lane holds (n' = nt*16+l16, c = strip+g4*4 .. +3) -> one 8B store
    float y0 = fmaxf(acc[0] + bv4[0], 0.f);
    float y1 = fmaxf(acc[1] + bv4[1], 0.f);
    float y2 = fmaxf(acc[2] + bv4[2], 0.f);
    float y3 = fmaxf(acc[3] + bv4[3], 0.f);
    uint2 u;
    u.x = (unsigned)f2b(y0) | ((unsigned)f2b(y1) << 16);
    u.y = (unsigned)f2b(y2) | ((unsigned)f2b(y3) << 16);
    size_t idx = ((size_t)brel * 16384 + n0 + nt * 16 + l16) * 64 + wvid * 8 + g4 * 2;
    *(uint2*)((unsigned*)dst + idx) = u;
  }
}

__global__ __launch_bounds__(512, 4) void k1_qkv(
    const float* __restrict__ rep,
    const float* __restrict__ wq, const float* __restrict__ bq,
    const float* __restrict__ wk, const float* __restrict__ bk,
    const float* __restrict__ wv, const float* __restrict__ bv,
    unsigned short* __restrict__ qo, unsigned short* __restrict__ ko,
    unsigned short* __restrict__ vo, int b0)
{
  extern __shared__ char smem[];
  char* XS = smem;   // 32K

  const int t = threadIdx.x;
  const int wvid = t >> 6, l = t & 63, l16 = l & 15, g4 = l >> 4;
  (void)l;
  const int brel = blockIdx.x >> 7;
  const int n0 = (blockIdx.x & 127) * 128;
  const int b = b0 + brel;

  // stage X^T: rep[b][c][n0+j] -> XS[j][c]  (float4-coalesced reads)
#pragma unroll
  for (int it = 0; it < 8; ++it) {
    int i = it * 512 + t;
    int c = i >> 5, j4 = i & 31;
    float4 xv = *(const float4*)(rep + (size_t)(b * 128 + c) * 16384 + n0 + j4 * 4);
    float vv[4] = {xv.x, xv.y, xv.z, xv.w};
#pragma unroll
    for (int r = 0; r < 4; ++r)
      *(unsigned short*)(XS + adr_q(j4 * 4 + r, c)) = f2b(vv[r]);
  }
  __syncthreads();

  k1_one(wq, bq, qo, XS, brel, n0, wvid, l16, g4);
  k1_one(wk, bk, ko, XS, brel, n0, wvid, l16, g4);
  k1_one(wv, bv, vo, XS, brel, n0, wvid, l16, g4);
}

// ================= K2: attention per (b,w) =================
// LDS: KS [256g][128c] @0 (64K), VTS [128c][256g] @64K (64K), P-slices @128K (8x4K)

__global__ __launch_bounds__(512, 2) void k2_attn(
    const unsigned short* __restrict__ qws, const unsigned short* __restrict__ kws,
    const unsigned short* __restrict__ vws, unsigned short* __restrict__ aws)
{
  extern __shared__ char smem[];
  char* KS  = smem;
  char* VTS = smem + (64 << 10);

  const int t = threadIdx.x;
  const int wvid = t >> 6, l = t & 63, l16 = l & 15, g4 = l >> 4;
  (void)l;
  char* PS = smem + (128 << 10) + (wvid << 12);

  const int brel = blockIdx.x >> 6;
  const int w = blockIdx.x & 63;
  const size_t base = (size_t)brel * 16384;

  // stage K rows [g][c]
#pragma unroll
  for (int it = 0; it < 8; ++it) {
    int i = it * 512 + t;
    int g = i >> 4, c16 = i & 15;
    short8 kv = *(const short8*)(kws + (base + g * 64 + w) * 128 + c16 * 8);
    *(short8*)(KS + adr_s(g, c16 * 8)) = kv;
  }
  // stage V^T [c][g] (scalar transpose writes, R1-verified formula)
#pragma unroll
  for (int it = 0; it < 8; ++it) {
    int i = it * 512 + t;
    int g = i >> 4, c16 = i & 15;
    short8 vv = *(const short8*)(vws + (base + g * 64 + w) * 128 + c16 * 8);
#pragma unroll
    for (int j = 0; j < 8; ++j)
      *(unsigned short*)(VTS + adr_vt(c16 * 8 + j, g)) = (unsigned short)vv[j];
  }
  __syncthreads();

  const float SCL2 = 0.08838834764831845f * 1.4426950408889634f; // rsqrt(128)*log2e
#pragma unroll
  for (int m = 0; m < 2; ++m) {
    const int hb = wvid * 32 + m * 16;
    short8 qa[4];
#pragma unroll
    for (int kk = 0; kk < 4; ++kk)
      qa[kk] = *(const short8*)(qws + (base + (hb + l16) * 64 + w) * 128 + kk * 32 + g4 * 8);

    // scores [16h][256g]
    f32x4 sc[16];
#pragma unroll
    for (int gt = 0; gt < 16; ++gt) {
      f32x4 acc = {0.f, 0.f, 0.f, 0.f};
#pragma unroll
      for (int kk = 0; kk < 4; ++kk) {
        short8 kb = ldsf(KS, adr_s(gt * 16 + l16, kk * 32 + g4 * 8));
        MFMA16(acc, qa[kk], kb);
      }
      sc[gt] = acc;
    }
    // softmax over g (g lives on l16 lanes x gt tiles; h = hb + g4*4 + r)
    float mx[4], rcps[4];
#pragma unroll
    for (int r = 0; r < 4; ++r) {
      float mm = sc[0][r];
#pragma unroll
      for (int gt = 1; gt < 16; ++gt) mm = fmaxf(mm, sc[gt][r]);
      mm = fmaxf(mm, __shfl_xor(mm, 1, 64));
      mm = fmaxf(mm, __shfl_xor(mm, 2, 64));
      mm = fmaxf(mm, __shfl_xor(mm, 4, 64));
      mm = fmaxf(mm, __shfl_xor(mm, 8, 64));
      mx[r] = mm;
    }
#pragma unroll
    for (int gt = 0; gt < 16; ++gt)
#pragma unroll
      for (int r = 0; r < 4; ++r)
        sc[gt][r] = exp2f((sc[gt][r] - mx[r]) * SCL2);
#pragma unroll
    for (int r = 0; r < 4; ++r) {
      float s = 0.f;
#pragma unroll
      for (int gt = 0; gt < 16; ++gt) s += sc[gt][r];
      s += __shfl_xor(s, 1, 64);
      s += __shfl_xor(s, 2, 64);
      s += __shfl_xor(s, 4, 64);
      s += __shfl_xor(s, 8, 64);
      rcps[r] = 1.0f / s;   // normalization deferred to PV output
    }
    // PV through wave-private P slice (write-scalar/read-b128, R1-verified)
    f32x4 oacc[8];
#pragma unroll
    for (int nt = 0; nt < 8; ++nt) oacc[nt] = (f32x4){0.f, 0.f, 0.f, 0.f};
#pragma unroll
    for (int gh = 0; gh < 2; ++gh) {
#pragma unroll
      for (int gt8 = 0; gt8 < 8; ++gt8) {
        int gt = gh * 8 + gt8;
        int gc = gt8 * 16 + l16;
#pragma unroll
        for (int r = 0; r < 4; ++r)
          *(unsigned short*)(PS + adr_s(g4 * 4 + r, gc)) = f2b(sc[gt][r]);
      }
#pragma unroll
      for (int kk = 0; kk < 4; ++kk) {
        short8 pa = ldsf(PS, adr_s(l16, kk * 32 + g4 * 8));
#pragma unroll
        for (int nt = 0; nt < 8; ++nt) {
          short8 vb = ldsf(VTS, adr_vt(nt * 16 + l16, gh * 128 + kk * 32 + g4 * 8));
          MFMA16(oacc[nt], pa, vb);
        }
      }
    }
    // normalize + direct scalar stores: att[n = h*64+w][c], h = hb+g4*4+r, c = nt*16+l16
#pragma unroll
    for (int nt = 0; nt < 8; ++nt) {
#pragma unroll
      for (int r = 0; r < 4; ++r) {
        size_t idx = (base + (size_t)(hb + g4 * 4 + r) * 64 + w) * 128 + nt * 16 + l16;
        aws[idx] = f2b(oacc[nt][r] * rcps[r]);
      }
    }
  }
}

// ================= K3: out = relu(wfc . att^T + bfc) =================
// grid = nbc*64; block tile = 256 n.  LDS: AS [256n][128c] (64K).

__global__ __launch_bounds__(512, 4) void k3_conv(
    const unsigned short* __restrict__ aws,
    const float* __restrict__ wfc, const float* __restrict__ bfc,
    float* __restrict__ out, int b0)
{
  extern __shared__ char smem[];
  char* AS = smem;

  const int t = threadIdx.x;
  const int wvid = t >> 6, l = t & 63, l16 = l & 15, g4 = l >> 4;
  (void)l;
  const int brel = blockIdx.x >> 6;
  const int n0 = (blockIdx.x & 63) * 256;
  const int b = b0 + brel;

#pragma unroll
  for (int it = 0; it < 8; ++it) {
    int i = it * 512 + t;
    int n = i >> 4, c16 = i & 15;
    short8 av = *(const short8*)(aws + ((size_t)brel * 16384 + n0 + n) * 128 + c16 * 8);
    *(short8*)(AS + adr_s(n, c16 * 8)) = av;
  }
  __syncthreads();

  const int strip = wvid * 16;
  short8 wf[4];
#pragma unroll
  for (int kk = 0; kk < 4; ++kk) wf[kk] = wfrag(wfc + (strip + l16) * 128, kk, g4);
  float bv4[4];
#pragma unroll
  for (int r = 0; r < 4; ++r) bv4[r] = bfc[strip + g4 * 4 + r];

#pragma unroll
  for (int nt = 0; nt < 16; ++nt) {
    f32x4 acc = {0.f, 0.f, 0.f, 0.f};
#pragma unroll
    for (int kk = 0; kk < 4; ++kk) {
      short8 ab = ldsf(AS, adr_s(nt * 16 + l16, kk * 32 + g4 * 8));
      MFMA16(acc, wf[kk], ab);
    }
#pragma unroll
    for (int r = 0; r < 4; ++r) {
      int o = strip + g4 * 4 + r;
      out[(size_t)(b * 128 + o) * 16384 + n0 + nt * 16 + l16] = fmaxf(acc[r] + bv4[r], 0.f);
    }
  }
}

extern "C" void kernel_launch(void* const* d_in, const int* in_sizes, int n_in,
                              void* d_out, int out_size, void* d_ws, size_t ws_size,
                              hipStream_t stream) {
  const float* rep = (const float*)d_in[0];
  const float* wq  = (const float*)d_in[1];
  const float* bq  = (const float*)d_in[2];
  const float* wk  = (const float*)d_in[3];
  const float* bk  = (const float*)d_in[4];
  const float* wv  = (const float*)d_in[5];
  const float* bv  = (const float*)d_in[6];
  const float* wfc = (const float*)d_in[7];
  const float* bfc = (const float*)d_in[8];
  float* out = (float*)d_out;
  (void)in_sizes; (void)n_in; (void)out_size;

  hipFuncSetAttribute((const void*)k2_attn, hipFuncAttributeMaxDynamicSharedMemorySize, 160 * 1024);
  hipFuncSetAttribute((const void*)k3_conv, hipFuncAttributeMaxDynamicSharedMemorySize, 64 * 1024);

  const size_t per_b = (size_t)16384 * 128 * 2;   // 4 MiB per array per b
  size_t nb_max = ws_size / (4 * per_b);
  int nb = (int)(nb_max < 16 ? nb_max : 16);
  if (nb < 1) return;  // needs >=16MB workspace

  char* ws = (char*)d_ws;
  unsigned short* qws = (unsigned short*)(ws);
  unsigned short* kws = (unsigned short*)(ws + (size_t)nb * per_b);
  unsigned short* vws = (unsigned short*)(ws + (size_t)nb * per_b * 2);
  unsigned short* aws = (unsigned short*)(ws + (size_t)nb * per_b * 3);

  for (int b0 = 0; b0 < 16; b0 += nb) {
    int nbc = (16 - b0) < nb ? (16 - b0) : nb;
    k1_qkv<<<dim3(nbc * 128), dim3(512), 32 * 1024, stream>>>(
        rep, wq, bq, wk, bk, wv, bv, qws, kws, vws, b0);
    k2_attn<<<dim3(nbc * 64), dim3(512), 160 * 1024, stream>>>(qws, kws, vws, aws);
    k3_conv<<<dim3(nbc * 64), dim3(512), 64 * 1024, stream>>>(aws, wfc, bfc, out, b0);
  }
}

// Round 4
// 264.757 us; speedup vs baseline: 2.6972x; 1.8274x over previous
//
#include <hip/hip_runtime.h>

// B=16, C=128, H=256, W=64.  3-kernel pipeline through bf16 workspace:
//  K1: Q/K/V = relu(Wx+b) -> ws [b][n=h*64+w][c] bf16; D-tiles staged through
//      LDS so global writes are full 256B rows (fixes 3.5x write amplification)
//  K2: per-(b,w) attention over H (R3-verified, untouched) -> att [b][n][c] bf16
//  K3: out = relu(wfc . att^T + bfc) -> [b][o][n] fp32 coalesced (untouched)

typedef __attribute__((ext_vector_type(8))) short short8;
typedef __attribute__((ext_vector_type(4))) float f32x4;

#define MFMA16(acc, a, b) (acc) = __builtin_amdgcn_mfma_f32_16x16x32_bf16((a), (b), (acc), 0, 0, 0)

__device__ __forceinline__ unsigned short f2b(float f) {
  unsigned u = __builtin_bit_cast(unsigned, f);
  u = (u + 0x7fffu + ((u >> 16) & 1u)) >> 16;   // RNE
  return (unsigned short)u;
}

// [R][128c] bf16 tile, row-XOR swizzle (verified write-scalar/read-b128 pair)
__device__ __forceinline__ unsigned adr_s(int r, int c) {
  return (unsigned)(((r << 8) + (c << 1)) ^ ((r & 7) << 4));
}
// K1's XS [128j][128c]: stronger row-hash (rows written in stride-4 bursts)
__device__ __forceinline__ unsigned adr_q(int r, int c) {
  return (unsigned)(((r << 8) + (c << 1)) ^ (((r ^ (r >> 3)) & 7) << 4));
}
// V^T tile [128c][256g] — R1/R3-verified formula
__device__ __forceinline__ unsigned adr_vt(int c, int g) {
  return (unsigned)(((c << 9) + (g << 1)) ^ ((c & 7) << 4));
}

__device__ __forceinline__ short8 ldsf(const char* p, unsigned off) {
  return *(const short8*)(p + off);
}

// 16-row x 32-k weight fragment from global fp32 row-major [128][128]
__device__ __forceinline__ short8 wfrag(const float* wrow, int kk, int g4) {
  const float* p = wrow + kk * 32 + g4 * 8;
  float4 a = *(const float4*)(p);
  float4 c = *(const float4*)(p + 4);
  short8 r;
  r[0] = (short)f2b(a.x); r[1] = (short)f2b(a.y);
  r[2] = (short)f2b(a.z); r[3] = (short)f2b(a.w);
  r[4] = (short)f2b(c.x); r[5] = (short)f2b(c.y);
  r[6] = (short)f2b(c.z); r[7] = (short)f2b(c.w);
  return r;
}

// ================= K1: QKV projection =================
// grid = nbc*128; block tile = 128 n.
// LDS: XS [128n][128c] @0 (32K), WS row-stage [128n][128c] @32K (32K).

__device__ __forceinline__ void k1_one(const float* wmat, const float* bias,
    unsigned short* dst, const char* XS, char* WS,
    int brel, int n0, int wvid, int l, int l16, int g4) {
  const int strip = wvid * 16;
  short8 wf[4];
#pragma unroll
  for (int kk = 0; kk < 4; ++kk) wf[kk] = wfrag(wmat + (strip + l16) * 128, kk, g4);
  float bv4[4];
#pragma unroll
  for (int r = 0; r < 4; ++r) bv4[r] = bias[strip + g4 * 4 + r];

  f32x4 acc[8];
#pragma unroll
  for (int nt = 0; nt < 8; ++nt) acc[nt] = (f32x4){0.f, 0.f, 0.f, 0.f};
#pragma unroll
  for (int nt = 0; nt < 8; ++nt) {
#pragma unroll
    for (int kk = 0; kk < 4; ++kk) {
      short8 xb = ldsf(XS, adr_q(nt * 16 + l16, kk * 32 + g4 * 8));
      MFMA16(acc[nt], wf[kk], xb);   // D[o][n']: col=l16 -> n', row=g4*4+r -> o
    }
  }
  __syncthreads();   // WS free: previous matrix's readback complete on all waves
  // stage: lane holds (n' = nt*16+l16, c = strip+g4*4 .. +3) -> uint2 into WS
#pragma unroll
  for (int nt = 0; nt < 8; ++nt) {
    float y0 = fmaxf(acc[nt][0] + bv4[0], 0.f);
    float y1 = fmaxf(acc[nt][1] + bv4[1], 0.f);
    float y2 = fmaxf(acc[nt][2] + bv4[2], 0.f);
    float y3 = fmaxf(acc[nt][3] + bv4[3], 0.f);
    uint2 u;
    u.x = (unsigned)f2b(y0) | ((unsigned)f2b(y1) << 16);
    u.y = (unsigned)f2b(y2) | ((unsigned)f2b(y3) << 16);
    int row = nt * 16 + l16;
    unsigned cb = (unsigned)(wvid * 32 + g4 * 8);          // byte col of c0
    *(uint2*)(WS + (unsigned)(row << 8) + (cb ^ ((unsigned)(row & 7) << 4))) = u;
  }
  __syncthreads();
  // readback: wave reads full rows (lane l -> dword l), 256B/row global stores
#pragma unroll
  for (int it = 0; it < 16; ++it) {
    int row = it * 8 + wvid;
    unsigned u = *(const unsigned*)(WS + (unsigned)(row << 8) +
                                   (((unsigned)(l << 2)) ^ ((unsigned)(row & 7) << 4)));
    ((unsigned*)dst)[(size_t)(brel * 16384 + n0 + row) * 64 + l] = u;
  }
}

__global__ __launch_bounds__(512, 4) void k1_qkv(
    const float* __restrict__ rep,
    const float* __restrict__ wq, const float* __restrict__ bq,
    const float* __restrict__ wk, const float* __restrict__ bk,
    const float* __restrict__ wv, const float* __restrict__ bv,
    unsigned short* __restrict__ qo, unsigned short* __restrict__ ko,
    unsigned short* __restrict__ vo, int b0)
{
  extern __shared__ char smem[];
  char* XS = smem;               // 32K
  char* WS = smem + (32 << 10);  // 32K

  const int t = threadIdx.x;
  const int wvid = t >> 6, l = t & 63, l16 = l & 15, g4 = l >> 4;
  const int brel = blockIdx.x >> 7;
  const int n0 = (blockIdx.x & 127) * 128;
  const int b = b0 + brel;

  // stage X^T: rep[b][c][n0+j] -> XS[j][c]  (float4-coalesced reads)
#pragma unroll
  for (int it = 0; it < 8; ++it) {
    int i = it * 512 + t;
    int c = i >> 5, j4 = i & 31;
    float4 xv = *(const float4*)(rep + (size_t)(b * 128 + c) * 16384 + n0 + j4 * 4);
    float vv[4] = {xv.x, xv.y, xv.z, xv.w};
#pragma unroll
    for (int r = 0; r < 4; ++r)
      *(unsigned short*)(XS + adr_q(j4 * 4 + r, c)) = f2b(vv[r]);
  }
  __syncthreads();

  k1_one(wq, bq, qo, XS, WS, brel, n0, wvid, l, l16, g4);
  k1_one(wk, bk, ko, XS, WS, brel, n0, wvid, l, l16, g4);
  k1_one(wv, bv, vo, XS, WS, brel, n0, wvid, l, l16, g4);
}

// ================= K2: attention per (b,w) — R3-verified, unchanged =========
// LDS: KS [256g][128c] @0 (64K), VTS [128c][256g] @64K (64K), P-slices @128K (8x4K)

__global__ __launch_bounds__(512, 2) void k2_attn(
    const unsigned short* __restrict__ qws, const unsigned short* __restrict__ kws,
    const unsigned short* __restrict__ vws, unsigned short* __restrict__ aws)
{
  extern __shared__ char smem[];
  char* KS  = smem;
  char* VTS = smem + (64 << 10);

  const int t = threadIdx.x;
  const int wvid = t >> 6, l = t & 63, l16 = l & 15, g4 = l >> 4;
  (void)l;
  char* PS = smem + (128 << 10) + (wvid << 12);

  const int brel = blockIdx.x >> 6;
  const int w = blockIdx.x & 63;
  const size_t base = (size_t)brel * 16384;

  // stage K rows [g][c]
#pragma unroll
  for (int it = 0; it < 8; ++it) {
    int i = it * 512 + t;
    int g = i >> 4, c16 = i & 15;
    short8 kv = *(const short8*)(kws + (base + g * 64 + w) * 128 + c16 * 8);
    *(short8*)(KS + adr_s(g, c16 * 8)) = kv;
  }
  // stage V^T [c][g] (scalar transpose writes)
#pragma unroll
  for (int it = 0; it < 8; ++it) {
    int i = it * 512 + t;
    int g = i >> 4, c16 = i & 15;
    short8 vv = *(const short8*)(vws + (base + g * 64 + w) * 128 + c16 * 8);
#pragma unroll
    for (int j = 0; j < 8; ++j)
      *(unsigned short*)(VTS + adr_vt(c16 * 8 + j, g)) = (unsigned short)vv[j];
  }
  __syncthreads();

  const float SCL2 = 0.08838834764831845f * 1.4426950408889634f; // rsqrt(128)*log2e
#pragma unroll
  for (int m = 0; m < 2; ++m) {
    const int hb = wvid * 32 + m * 16;
    short8 qa[4];
#pragma unroll
    for (int kk = 0; kk < 4; ++kk)
      qa[kk] = *(const short8*)(qws + (base + (hb + l16) * 64 + w) * 128 + kk * 32 + g4 * 8);

    // scores [16h][256g]
    f32x4 sc[16];
#pragma unroll
    for (int gt = 0; gt < 16; ++gt) {
      f32x4 acc = {0.f, 0.f, 0.f, 0.f};
#pragma unroll
      for (int kk = 0; kk < 4; ++kk) {
        short8 kb = ldsf(KS, adr_s(gt * 16 + l16, kk * 32 + g4 * 8));
        MFMA16(acc, qa[kk], kb);
      }
      sc[gt] = acc;
    }
    // softmax over g (g lives on l16 lanes x gt tiles; h = hb + g4*4 + r)
    float mx[4], rcps[4];
#pragma unroll
    for (int r = 0; r < 4; ++r) {
      float mm = sc[0][r];
#pragma unroll
      for (int gt = 1; gt < 16; ++gt) mm = fmaxf(mm, sc[gt][r]);
      mm = fmaxf(mm, __shfl_xor(mm, 1, 64));
      mm = fmaxf(mm, __shfl_xor(mm, 2, 64));
      mm = fmaxf(mm, __shfl_xor(mm, 4, 64));
      mm = fmaxf(mm, __shfl_xor(mm, 8, 64));
      mx[r] = mm;
    }
#pragma unroll
    for (int gt = 0; gt < 16; ++gt)
#pragma unroll
      for (int r = 0; r < 4; ++r)
        sc[gt][r] = exp2f((sc[gt][r] - mx[r]) * SCL2);
#pragma unroll
    for (int r = 0; r < 4; ++r) {
      float s = 0.f;
#pragma unroll
      for (int gt = 0; gt < 16; ++gt) s += sc[gt][r];
      s += __shfl_xor(s, 1, 64);
      s += __shfl_xor(s, 2, 64);
      s += __shfl_xor(s, 4, 64);
      s += __shfl_xor(s, 8, 64);
      rcps[r] = 1.0f / s;   // normalization deferred to PV output
    }
    // PV through wave-private P slice (write-scalar/read-b128)
    f32x4 oacc[8];
#pragma unroll
    for (int nt = 0; nt < 8; ++nt) oacc[nt] = (f32x4){0.f, 0.f, 0.f, 0.f};
#pragma unroll
    for (int gh = 0; gh < 2; ++gh) {
#pragma unroll
      for (int gt8 = 0; gt8 < 8; ++gt8) {
        int gt = gh * 8 + gt8;
        int gc = gt8 * 16 + l16;
#pragma unroll
        for (int r = 0; r < 4; ++r)
          *(unsigned short*)(PS + adr_s(g4 * 4 + r, gc)) = f2b(sc[gt][r]);
      }
#pragma unroll
      for (int kk = 0; kk < 4; ++kk) {
        short8 pa = ldsf(PS, adr_s(l16, kk * 32 + g4 * 8));
#pragma unroll
        for (int nt = 0; nt < 8; ++nt) {
          short8 vb = ldsf(VTS, adr_vt(nt * 16 + l16, gh * 128 + kk * 32 + g4 * 8));
          MFMA16(oacc[nt], pa, vb);
        }
      }
    }
    // normalize + direct scalar stores: att[n = h*64+w][c], h = hb+g4*4+r, c = nt*16+l16
#pragma unroll
    for (int nt = 0; nt < 8; ++nt) {
#pragma unroll
      for (int r = 0; r < 4; ++r) {
        size_t idx = (base + (size_t)(hb + g4 * 4 + r) * 64 + w) * 128 + nt * 16 + l16;
        aws[idx] = f2b(oacc[nt][r] * rcps[r]);
      }
    }
  }
}

// ================= K3: out = relu(wfc . att^T + bfc) — unchanged =============
// grid = nbc*64; block tile = 256 n.  LDS: AS [256n][128c] (64K).

__global__ __launch_bounds__(512, 4) void k3_conv(
    const unsigned short* __restrict__ aws,
    const float* __restrict__ wfc, const float* __restrict__ bfc,
    float* __restrict__ out, int b0)
{
  extern __shared__ char smem[];
  char* AS = smem;

  const int t = threadIdx.x;
  const int wvid = t >> 6, l = t & 63, l16 = l & 15, g4 = l >> 4;
  (void)l;
  const int brel = blockIdx.x >> 6;
  const int n0 = (blockIdx.x & 63) * 256;
  const int b = b0 + brel;

#pragma unroll
  for (int it = 0; it < 8; ++it) {
    int i = it * 512 + t;
    int n = i >> 4, c16 = i & 15;
    short8 av = *(const short8*)(aws + ((size_t)brel * 16384 + n0 + n) * 128 + c16 * 8);
    *(short8*)(AS + adr_s(n, c16 * 8)) = av;
  }
  __syncthreads();

  const int strip = wvid * 16;
  short8 wf[4];
#pragma unroll
  for (int kk = 0; kk < 4; ++kk) wf[kk] = wfrag(wfc + (strip + l16) * 128, kk, g4);
  float bv4[4];
#pragma unroll
  for (int r = 0; r < 4; ++r) bv4[r] = bfc[strip + g4 * 4 + r];

#pragma unroll
  for (int nt = 0; nt < 16; ++nt) {
    f32x4 acc = {0.f, 0.f, 0.f, 0.f};
#pragma unroll
    for (int kk = 0; kk < 4; ++kk) {
      short8 ab = ldsf(AS, adr_s(nt * 16 + l16, kk * 32 + g4 * 8));
      MFMA16(acc, wf[kk], ab);
    }
#pragma unroll
    for (int r = 0; r < 4; ++r) {
      int o = strip + g4 * 4 + r;
      out[(size_t)(b * 128 + o) * 16384 + n0 + nt * 16 + l16] = fmaxf(acc[r] + bv4[r], 0.f);
    }
  }
}

extern "C" void kernel_launch(void* const* d_in, const int* in_sizes, int n_in,
                              void* d_out, int out_size, void* d_ws, size_t ws_size,
                              hipStream_t stream) {
  const float* rep = (const float*)d_in[0];
  const float* wq  = (const float*)d_in[1];
  const float* bq  = (const float*)d_in[2];
  const float* wk  = (const float*)d_in[3];
  const float* bk  = (const float*)d_in[4];
  const float* wv  = (const float*)d_in[5];
  const float* bv  = (const float*)d_in[6];
  const float* wfc = (const float*)d_in[7];
  const float* bfc = (const float*)d_in[8];
  float* out = (float*)d_out;
  (void)in_sizes; (void)n_in; (void)out_size;

  hipFuncSetAttribute((const void*)k1_qkv,  hipFuncAttributeMaxDynamicSharedMemorySize, 64 * 1024);
  hipFuncSetAttribute((const void*)k2_attn, hipFuncAttributeMaxDynamicSharedMemorySize, 160 * 1024);
  hipFuncSetAttribute((const void*)k3_conv, hipFuncAttributeMaxDynamicSharedMemorySize, 64 * 1024);

  const size_t per_b = (size_t)16384 * 128 * 2;   // 4 MiB per array per b
  size_t nb_max = ws_size / (4 * per_b);
  int nb = (int)(nb_max < 16 ? nb_max : 16);
  if (nb < 1) return;  // needs >=16MB workspace

  char* ws = (char*)d_ws;
  unsigned short* qws = (unsigned short*)(ws);
  unsigned short* kws = (unsigned short*)(ws + (size_t)nb * per_b);
  unsigned short* vws = (unsigned short*)(ws + (size_t)nb * per_b * 2);
  unsigned short* aws = (unsigned short*)(ws + (size_t)nb * per_b * 3);

  for (int b0 = 0; b0 < 16; b0 += nb) {
    int nbc = (16 - b0) < nb ? (16 - b0) : nb;
    k1_qkv<<<dim3(nbc * 128), dim3(512), 64 * 1024, stream>>>(
        rep, wq, bq, wk, bk, wv, bv, qws, kws, vws, b0);
    k2_attn<<<dim3(nbc * 64), dim3(512), 160 * 1024, stream>>>(qws, kws, vws, aws);
    k3_conv<<<dim3(nbc * 64), dim3(512), 64 * 1024, stream>>>(aws, wfc, bfc, out, b0);
  }
}

// Round 5
// 255.563 us; speedup vs baseline: 2.7942x; 1.0360x over previous
//
#include <hip/hip_runtime.h>

// B=16, C=128, H=256, W=64.  3-kernel pipeline through bf16 workspace:
//  K1: Q/K/V = relu(Wx+b) -> ws [b][n=h*64+w][c] bf16; row-staged writes (R4-verified)
//  K2: per-(b,w) attention over H. 16 waves/block (one 16-row m-tile each),
//      conflict-fixed V^T swizzle, quarter-P wave-private staging.
//  K3: out = relu(wfc . att^T + bfc) -> [b][o][n] fp32 coalesced (R4-verified)

typedef __attribute__((ext_vector_type(8))) short short8;
typedef __attribute__((ext_vector_type(4))) float f32x4;

#define MFMA16(acc, a, b) (acc) = __builtin_amdgcn_mfma_f32_16x16x32_bf16((a), (b), (acc), 0, 0, 0)

__device__ __forceinline__ unsigned short f2b(float f) {
  unsigned u = __builtin_bit_cast(unsigned, f);
  u = (u + 0x7fffu + ((u >> 16) & 1u)) >> 16;   // RNE
  return (unsigned short)u;
}

// [R][128c] bf16 tile, row-XOR swizzle (verified write-scalar/read-b128 pair)
__device__ __forceinline__ unsigned adr_s(int r, int c) {
  return (unsigned)(((r << 8) + (c << 1)) ^ ((r & 7) << 4));
}
// K1's XS [128j][128c]: stronger row-hash (rows written in stride-4 bursts)
__device__ __forceinline__ unsigned adr_q(int r, int c) {
  return (unsigned)(((r << 8) + (c << 1)) ^ (((r ^ (r >> 3)) & 7) << 4));
}
// V^T tile [128c][256g]: 16B-block index XORs BOTH c&7 (spreads read lanes,
// c-stride 1) and (c>>3)&7 (spreads write lanes, c-stride 8). g&7 stays in-block
// so b128 reads of 8 consecutive g remain contiguous.
__device__ __forceinline__ unsigned adr_vt(int c, int g) {
  unsigned blk = (unsigned)(((g >> 3) ^ (c & 7) ^ ((c >> 3) & 7)) & 31);
  return (unsigned)((c << 9) + (blk << 4) + ((g & 7) << 1));
}
// per-wave P quarter-slice [16r][64c] bf16 (2KB), row-hash
__device__ __forceinline__ unsigned ps_adr(int r, int c) {
  return (unsigned)(((r << 7) + (c << 1)) ^ (((r ^ (r >> 3)) & 7) << 4));
}

__device__ __forceinline__ short8 ldsf(const char* p, unsigned off) {
  return *(const short8*)(p + off);
}

// 16-row x 32-k weight fragment from global fp32 row-major [128][128]
__device__ __forceinline__ short8 wfrag(const float* wrow, int kk, int g4) {
  const float* p = wrow + kk * 32 + g4 * 8;
  float4 a = *(const float4*)(p);
  float4 c = *(const float4*)(p + 4);
  short8 r;
  r[0] = (short)f2b(a.x); r[1] = (short)f2b(a.y);
  r[2] = (short)f2b(a.z); r[3] = (short)f2b(a.w);
  r[4] = (short)f2b(c.x); r[5] = (short)f2b(c.y);
  r[6] = (short)f2b(c.z); r[7] = (short)f2b(c.w);
  return r;
}

// ================= K1: QKV projection (R4-verified, unchanged) =================
// grid = nbc*128; block tile = 128 n.
// LDS: XS [128n][128c] @0 (32K), WS row-stage [128n][128c] @32K (32K).

__device__ __forceinline__ void k1_one(const float* wmat, const float* bias,
    unsigned short* dst, const char* XS, char* WS,
    int brel, int n0, int wvid, int l, int l16, int g4) {
  const int strip = wvid * 16;
  short8 wf[4];
#pragma unroll
  for (int kk = 0; kk < 4; ++kk) wf[kk] = wfrag(wmat + (strip + l16) * 128, kk, g4);
  float bv4[4];
#pragma unroll
  for (int r = 0; r < 4; ++r) bv4[r] = bias[strip + g4 * 4 + r];

  f32x4 acc[8];
#pragma unroll
  for (int nt = 0; nt < 8; ++nt) acc[nt] = (f32x4){0.f, 0.f, 0.f, 0.f};
#pragma unroll
  for (int nt = 0; nt < 8; ++nt) {
#pragma unroll
    for (int kk = 0; kk < 4; ++kk) {
      short8 xb = ldsf(XS, adr_q(nt * 16 + l16, kk * 32 + g4 * 8));
      MFMA16(acc[nt], wf[kk], xb);   // D[o][n']: col=l16 -> n', row=g4*4+r -> o
    }
  }
  __syncthreads();   // WS free: previous matrix's readback complete on all waves
#pragma unroll
  for (int nt = 0; nt < 8; ++nt) {
    float y0 = fmaxf(acc[nt][0] + bv4[0], 0.f);
    float y1 = fmaxf(acc[nt][1] + bv4[1], 0.f);
    float y2 = fmaxf(acc[nt][2] + bv4[2], 0.f);
    float y3 = fmaxf(acc[nt][3] + bv4[3], 0.f);
    uint2 u;
    u.x = (unsigned)f2b(y0) | ((unsigned)f2b(y1) << 16);
    u.y = (unsigned)f2b(y2) | ((unsigned)f2b(y3) << 16);
    int row = nt * 16 + l16;
    unsigned cb = (unsigned)(wvid * 32 + g4 * 8);
    *(uint2*)(WS + (unsigned)(row << 8) + (cb ^ ((unsigned)(row & 7) << 4))) = u;
  }
  __syncthreads();
#pragma unroll
  for (int it = 0; it < 16; ++it) {
    int row = it * 8 + wvid;
    unsigned u = *(const unsigned*)(WS + (unsigned)(row << 8) +
                                   (((unsigned)(l << 2)) ^ ((unsigned)(row & 7) << 4)));
    ((unsigned*)dst)[(size_t)(brel * 16384 + n0 + row) * 64 + l] = u;
  }
}

__global__ __launch_bounds__(512, 4) void k1_qkv(
    const float* __restrict__ rep,
    const float* __restrict__ wq, const float* __restrict__ bq,
    const float* __restrict__ wk, const float* __restrict__ bk,
    const float* __restrict__ wv, const float* __restrict__ bv,
    unsigned short* __restrict__ qo, unsigned short* __restrict__ ko,
    unsigned short* __restrict__ vo, int b0)
{
  extern __shared__ char smem[];
  char* XS = smem;               // 32K
  char* WS = smem + (32 << 10);  // 32K

  const int t = threadIdx.x;
  const int wvid = t >> 6, l = t & 63, l16 = l & 15, g4 = l >> 4;
  const int brel = blockIdx.x >> 7;
  const int n0 = (blockIdx.x & 127) * 128;
  const int b = b0 + brel;

#pragma unroll
  for (int it = 0; it < 8; ++it) {
    int i = it * 512 + t;
    int c = i >> 5, j4 = i & 31;
    float4 xv = *(const float4*)(rep + (size_t)(b * 128 + c) * 16384 + n0 + j4 * 4);
    float vv[4] = {xv.x, xv.y, xv.z, xv.w};
#pragma unroll
    for (int r = 0; r < 4; ++r)
      *(unsigned short*)(XS + adr_q(j4 * 4 + r, c)) = f2b(vv[r]);
  }
  __syncthreads();

  k1_one(wq, bq, qo, XS, WS, brel, n0, wvid, l, l16, g4);
  k1_one(wk, bk, ko, XS, WS, brel, n0, wvid, l, l16, g4);
  k1_one(wv, bv, vo, XS, WS, brel, n0, wvid, l, l16, g4);
}

// ================= K2: attention per (b,w) — 16 waves =================
// LDS: KS [256g][128c] @0 (64K), VTS [128c][256g] @64K (64K),
//      PS quarter-slices @128K (16 waves x 2K = 32K). Total 160K.

__global__ __launch_bounds__(1024, 1) void k2_attn(
    const unsigned short* __restrict__ qws, const unsigned short* __restrict__ kws,
    const unsigned short* __restrict__ vws, unsigned short* __restrict__ aws)
{
  extern __shared__ char smem[];
  char* KS  = smem;
  char* VTS = smem + (64 << 10);

  const int t = threadIdx.x;
  const int wvid = t >> 6, l = t & 63, l16 = l & 15, g4 = l >> 4;
  char* PS = smem + (128 << 10) + (wvid << 11);

  const int brel = blockIdx.x >> 6;
  const int w = blockIdx.x & 63;
  const size_t base = (size_t)brel * 16384;

  // stage K rows [g][c] (vector write, conflict-free)
#pragma unroll
  for (int it = 0; it < 4; ++it) {
    int i = it * 1024 + t;
    int g = i >> 4, c16 = i & 15;
    short8 kv = *(const short8*)(kws + (base + g * 64 + w) * 128 + c16 * 8);
    *(short8*)(KS + adr_s(g, c16 * 8)) = kv;
  }
  // stage V^T [c][g] (scalar transpose, double-XOR swizzle)
#pragma unroll
  for (int it = 0; it < 4; ++it) {
    int i = it * 1024 + t;
    int g = i >> 4, c16 = i & 15;
    short8 vv = *(const short8*)(vws + (base + g * 64 + w) * 128 + c16 * 8);
#pragma unroll
    for (int j = 0; j < 8; ++j)
      *(unsigned short*)(VTS + adr_vt(c16 * 8 + j, g)) = (unsigned short)vv[j];
  }
  __syncthreads();

  const float SCL2 = 0.08838834764831845f * 1.4426950408889634f; // rsqrt(128)*log2e
  const int hb = wvid * 16;   // this wave's 16 h-rows

  short8 qa[4];
#pragma unroll
  for (int kk = 0; kk < 4; ++kk)
    qa[kk] = *(const short8*)(qws + (base + (hb + l16) * 64 + w) * 128 + kk * 32 + g4 * 8);

  // scores [16h][256g]
  f32x4 sc[16];
#pragma unroll
  for (int gt = 0; gt < 16; ++gt) {
    f32x4 acc = {0.f, 0.f, 0.f, 0.f};
#pragma unroll
    for (int kk = 0; kk < 4; ++kk) {
      short8 kb = ldsf(KS, adr_s(gt * 16 + l16, kk * 32 + g4 * 8));
      MFMA16(acc, qa[kk], kb);
    }
    sc[gt] = acc;
  }
  // softmax over g (g lives on l16 lanes x gt tiles; h = hb + g4*4 + r)
  float mx[4], rcps[4];
#pragma unroll
  for (int r = 0; r < 4; ++r) {
    float mm = sc[0][r];
#pragma unroll
    for (int gt = 1; gt < 16; ++gt) mm = fmaxf(mm, sc[gt][r]);
    mm = fmaxf(mm, __shfl_xor(mm, 1, 64));
    mm = fmaxf(mm, __shfl_xor(mm, 2, 64));
    mm = fmaxf(mm, __shfl_xor(mm, 4, 64));
    mm = fmaxf(mm, __shfl_xor(mm, 8, 64));
    mx[r] = mm;
  }
#pragma unroll
  for (int gt = 0; gt < 16; ++gt)
#pragma unroll
    for (int r = 0; r < 4; ++r)
      sc[gt][r] = exp2f((sc[gt][r] - mx[r]) * SCL2);
#pragma unroll
  for (int r = 0; r < 4; ++r) {
    float s = 0.f;
#pragma unroll
    for (int gt = 0; gt < 16; ++gt) s += sc[gt][r];
    s += __shfl_xor(s, 1, 64);
    s += __shfl_xor(s, 2, 64);
    s += __shfl_xor(s, 4, 64);
    s += __shfl_xor(s, 8, 64);
    rcps[r] = 1.0f / s;   // normalization deferred to PV output
  }

  // PV over 4 g-quarters through wave-private 2K P slice (in-wave DS ordering)
  f32x4 oacc[8];
#pragma unroll
  for (int nt = 0; nt < 8; ++nt) oacc[nt] = (f32x4){0.f, 0.f, 0.f, 0.f};
#pragma unroll
  for (int gh = 0; gh < 4; ++gh) {
#pragma unroll
    for (int gt4 = 0; gt4 < 4; ++gt4) {
      int gt = gh * 4 + gt4;
      int gc = gt4 * 16 + l16;
#pragma unroll
      for (int r = 0; r < 4; ++r)
        *(unsigned short*)(PS + ps_adr(g4 * 4 + r, gc)) = f2b(sc[gt][r]);
    }
#pragma unroll
    for (int kk2 = 0; kk2 < 2; ++kk2) {
      short8 pa = ldsf(PS, ps_adr(l16, kk2 * 32 + g4 * 8));
#pragma unroll
      for (int nt = 0; nt < 8; ++nt) {
        short8 vb = ldsf(VTS, adr_vt(nt * 16 + l16, gh * 64 + kk2 * 32 + g4 * 8));
        MFMA16(oacc[nt], pa, vb);
      }
    }
  }
  // normalize + direct scalar stores: att[n = h*64+w][c], h = hb+g4*4+r, c = nt*16+l16
#pragma unroll
  for (int nt = 0; nt < 8; ++nt) {
#pragma unroll
    for (int r = 0; r < 4; ++r) {
      size_t idx = (base + (size_t)(hb + g4 * 4 + r) * 64 + w) * 128 + nt * 16 + l16;
      aws[idx] = f2b(oacc[nt][r] * rcps[r]);
    }
  }
}

// ================= K3: out = relu(wfc . att^T + bfc) — unchanged =============
// grid = nbc*64; block tile = 256 n.  LDS: AS [256n][128c] (64K).

__global__ __launch_bounds__(512, 4) void k3_conv(
    const unsigned short* __restrict__ aws,
    const float* __restrict__ wfc, const float* __restrict__ bfc,
    float* __restrict__ out, int b0)
{
  extern __shared__ char smem[];
  char* AS = smem;

  const int t = threadIdx.x;
  const int wvid = t >> 6, l = t & 63, l16 = l & 15, g4 = l >> 4;
  (void)l;
  const int brel = blockIdx.x >> 6;
  const int n0 = (blockIdx.x & 63) * 256;
  const int b = b0 + brel;

#pragma unroll
  for (int it = 0; it < 8; ++it) {
    int i = it * 512 + t;
    int n = i >> 4, c16 = i & 15;
    short8 av = *(const short8*)(aws + ((size_t)brel * 16384 + n0 + n) * 128 + c16 * 8);
    *(short8*)(AS + adr_s(n, c16 * 8)) = av;
  }
  __syncthreads();

  const int strip = wvid * 16;
  short8 wf[4];
#pragma unroll
  for (int kk = 0; kk < 4; ++kk) wf[kk] = wfrag(wfc + (strip + l16) * 128, kk, g4);
  float bv4[4];
#pragma unroll
  for (int r = 0; r < 4; ++r) bv4[r] = bfc[strip + g4 * 4 + r];

#pragma unroll
  for (int nt = 0; nt < 16; ++nt) {
    f32x4 acc = {0.f, 0.f, 0.f, 0.f};
#pragma unroll
    for (int kk = 0; kk < 4; ++kk) {
      short8 ab = ldsf(AS, adr_s(nt * 16 + l16, kk * 32 + g4 * 8));
      MFMA16(acc, wf[kk], ab);
    }
#pragma unroll
    for (int r = 0; r < 4; ++r) {
      int o = strip + g4 * 4 + r;
      out[(size_t)(b * 128 + o) * 16384 + n0 + nt * 16 + l16] = fmaxf(acc[r] + bv4[r], 0.f);
    }
  }
}

extern "C" void kernel_launch(void* const* d_in, const int* in_sizes, int n_in,
                              void* d_out, int out_size, void* d_ws, size_t ws_size,
                              hipStream_t stream) {
  const float* rep = (const float*)d_in[0];
  const float* wq  = (const float*)d_in[1];
  const float* bq  = (const float*)d_in[2];
  const float* wk  = (const float*)d_in[3];
  const float* bk  = (const float*)d_in[4];
  const float* wv  = (const float*)d_in[5];
  const float* bv  = (const float*)d_in[6];
  const float* wfc = (const float*)d_in[7];
  const float* bfc = (const float*)d_in[8];
  float* out = (float*)d_out;
  (void)in_sizes; (void)n_in; (void)out_size;

  hipFuncSetAttribute((const void*)k1_qkv,  hipFuncAttributeMaxDynamicSharedMemorySize, 64 * 1024);
  hipFuncSetAttribute((const void*)k2_attn, hipFuncAttributeMaxDynamicSharedMemorySize, 160 * 1024);
  hipFuncSetAttribute((const void*)k3_conv, hipFuncAttributeMaxDynamicSharedMemorySize, 64 * 1024);

  const size_t per_b = (size_t)16384 * 128 * 2;   // 4 MiB per array per b
  size_t nb_max = ws_size / (4 * per_b);
  int nb = (int)(nb_max < 16 ? nb_max : 16);
  if (nb < 1) return;  // needs >=16MB workspace

  char* ws = (char*)d_ws;
  unsigned short* qws = (unsigned short*)(ws);
  unsigned short* kws = (unsigned short*)(ws + (size_t)nb * per_b);
  unsigned short* vws = (unsigned short*)(ws + (size_t)nb * per_b * 2);
  unsigned short* aws = (unsigned short*)(ws + (size_t)nb * per_b * 3);

  for (int b0 = 0; b0 < 16; b0 += nb) {
    int nbc = (16 - b0) < nb ? (16 - b0) : nb;
    k1_qkv<<<dim3(nbc * 128), dim3(512), 64 * 1024, stream>>>(
        rep, wq, bq, wk, bk, wv, bv, qws, kws, vws, b0);
    k2_attn<<<dim3(nbc * 64), dim3(1024), 160 * 1024, stream>>>(qws, kws, vws, aws);
    k3_conv<<<dim3(nbc * 64), dim3(512), 64 * 1024, stream>>>(aws, wfc, bfc, out, b0);
  }
}